// Round 2
// baseline (471.340 us; speedup 1.0000x reference)
//
#include <hip/hip_runtime.h>

#define D 128
#define NLAYERS 5

using short8  = __attribute__((ext_vector_type(8))) short;
using short4v = __attribute__((ext_vector_type(4))) short;
using floatx4 = __attribute__((ext_vector_type(4))) float;

__device__ __forceinline__ unsigned bf16_rne(float x) {
    unsigned u = __float_as_uint(x);
    return (u + 0x7fffu + ((u >> 16) & 1u)) >> 16;
}
__device__ __forceinline__ float bf16_to_f32(short s) {
    return __uint_as_float(((unsigned)(unsigned short)s) << 16);
}

// ---------------- prepA: zero deg/pooled + W transpose/bf16 + gather (independent work) ----------------
__global__ void prepA_kernel(const int* __restrict__ x, const float* __restrict__ emb,
                             const float* __restrict__ Wa, const float* __restrict__ Wb,
                             short* __restrict__ H0, short* __restrict__ wt,
                             int* __restrict__ deg, float* __restrict__ pooled,
                             int n_nodes) {
    const int gtid = blockIdx.x * 256 + threadIdx.x;
    const int gsz  = gridDim.x * 256;
    for (int i = gtid; i < n_nodes; i += gsz) deg[i] = 0;
    if (gtid < 128) pooled[gtid] = 0.f;
    for (int g = gtid; g < 2 * NLAYERS * D * D; g += gsz) {
        int mat = g >> 14, idx = g & 16383;
        int n = idx >> 7, k = idx & 127;
        const float* W = (mat & 1) ? (Wb + (size_t)(mat >> 1) * D * D)
                                   : (Wa + (size_t)(mat >> 1) * D * D);
        wt[g] = (short)bf16_rne(W[k * D + n]);
    }
    for (int t = gtid; t < n_nodes * 32; t += gsz) {
        int node = t >> 5, lane = t & 31;
        int s = x[node];
        const float4 v = *reinterpret_cast<const float4*>(emb + (size_t)s * D + lane * 4);
        short4v o;
        o[0] = (short)bf16_rne(v.x); o[1] = (short)bf16_rne(v.y);
        o[2] = (short)bf16_rne(v.z); o[3] = (short)bf16_rne(v.w);
        *reinterpret_cast<short4v*>(H0 + (size_t)node * D + lane * 4) = o;
    }
}

// ---------------- CSR build (R8-exact) ----------------
__global__ void hist_kernel(const int* __restrict__ edst, int* __restrict__ deg, int n_edges) {
    int e = blockIdx.x * 256 + threadIdx.x;
    if (e < n_edges) atomicAdd(&deg[edst[e]], 1);
}

#define SCAN_TILE 1024
__global__ void scan_sums_kernel(const int* __restrict__ deg, int* __restrict__ bsums, int n) {
    __shared__ int red[256];
    int base = blockIdx.x * SCAN_TILE + threadIdx.x * 4;
    int s = 0;
    #pragma unroll
    for (int j = 0; j < 4; j++) {
        int i = base + j;
        if (i < n) s += deg[i];
    }
    red[threadIdx.x] = s;
    __syncthreads();
    for (int off = 128; off > 0; off >>= 1) {
        if (threadIdx.x < off) red[threadIdx.x] += red[threadIdx.x + off];
        __syncthreads();
    }
    if (threadIdx.x == 0) bsums[blockIdx.x] = red[0];
}

__global__ void scan_bsums_kernel(int* __restrict__ bsums, int nblocks) {
    __shared__ int sdata[256];
    int carry = 0;
    for (int base = 0; base < nblocks; base += 256) {
        int i = base + threadIdx.x;
        int v = (i < nblocks) ? bsums[i] : 0;
        sdata[threadIdx.x] = v;
        __syncthreads();
        for (int off = 1; off < 256; off <<= 1) {
            int t = (threadIdx.x >= off) ? sdata[threadIdx.x - off] : 0;
            __syncthreads();
            sdata[threadIdx.x] += t;
            __syncthreads();
        }
        int incl = sdata[threadIdx.x];
        if (i < nblocks) bsums[i] = carry + incl - v;
        carry += sdata[255];
        __syncthreads();
    }
}

__global__ void scan_final_kernel(const int* __restrict__ deg, const int* __restrict__ bsums,
                                  int* __restrict__ offsets, int* __restrict__ cursor, int n) {
    __shared__ int sdata[256];
    int base = blockIdx.x * SCAN_TILE + threadIdx.x * 4;
    int v[4];
    int s = 0;
    #pragma unroll
    for (int j = 0; j < 4; j++) {
        int i = base + j;
        v[j] = (i < n) ? deg[i] : 0;
        s += v[j];
    }
    sdata[threadIdx.x] = s;
    __syncthreads();
    for (int off = 1; off < 256; off <<= 1) {
        int t = (threadIdx.x >= off) ? sdata[threadIdx.x - off] : 0;
        __syncthreads();
        sdata[threadIdx.x] += t;
        __syncthreads();
    }
    int excl = sdata[threadIdx.x] - s + bsums[blockIdx.x];
    #pragma unroll
    for (int j = 0; j < 4; j++) {
        int i = base + j;
        if (i <= n) offsets[i] = excl;
        if (i < n) cursor[i] = excl;
        excl += v[j];
    }
}

__global__ void fill_kernel(const int* __restrict__ esrc, const int* __restrict__ edst,
                            int* __restrict__ cursor, int* __restrict__ csr_src, int n_edges) {
    int e = blockIdx.x * 256 + threadIdx.x;
    if (e >= n_edges) return;
    int pos = atomicAdd(&cursor[edst[e]], 1);
    csr_src[pos] = esrc[e];
}

// ---------------- fused layer (R8-exact math) + optional fused pool on last layer ----------------
// block: 64 nodes, 512 threads (8 waves).
// Aggregation: 16 lanes/node, ONE contiguous 16B chunk per lane -> one gather instruction per
// edge touching each 64B line of the source row exactly once (the old 8-lane x 2-strided-16B
// layout touched every line twice and issued 2x the instructions). Each thread owns 2 rows
// (rA, rA+32); their edge loops are jointly 4+4-unrolled so 8 x 16B loads stay in flight.
// Per-row edge order and the (a+b)+(c+d) add tree are unchanged -> math identical.
// LDS: zsh 16KB + ONE shared weight buffer 32KB = 48KB -> 3 blocks/CU.
// 16B chunks XOR-swizzled: chunk c of row r at (c ^ (r&15)).
__global__ __launch_bounds__(512, 6) void layer_kernel(
        const int* __restrict__ offsets, const int* __restrict__ csr_src,
        const short* __restrict__ h_in, const short* __restrict__ wta,
        const short* __restrict__ wtb, const float* __restrict__ ba,
        const float* __restrict__ bb, short* __restrict__ h_out,
        float* __restrict__ pooled_accum, int n_rows) {
    __shared__ __align__(16) short zsh[64 * 128];     // z tile, then t tile, then pool scratch
    __shared__ __align__(16) short wsh[128 * 128];    // wa for GEMM1, then wb for GEMM2

    const int tid  = threadIdx.x;
    const int row0 = blockIdx.x * 64;

    #pragma unroll
    for (int i = 0; i < 4; i++) {
        int g = i * 512 + tid;
        int n = g >> 4, c = g & 15;
        int off = (n * 16 + (c ^ (n & 15))) * 8;
        *reinterpret_cast<short8*>(&wsh[off]) =
            *reinterpret_cast<const short8*>(wta + n * D + c * 8);
    }

    {
        const int rA  = tid >> 4;        // 0..31
        const int rB  = rA + 32;
        const int l16 = tid & 15;
        const int grA = row0 + rA;
        const int grB = row0 + rB;
        float accA[8], accB[8];
        int eA = 0, endA = 0, eB = 0, endB = 0;
        if (grA < n_rows) {
            short8 s = *reinterpret_cast<const short8*>(h_in + (size_t)grA * D + l16 * 8);
            #pragma unroll
            for (int j = 0; j < 8; j++) accA[j] = bf16_to_f32(s[j]);
            eA = offsets[grA]; endA = offsets[grA + 1];
        } else {
            #pragma unroll
            for (int j = 0; j < 8; j++) accA[j] = 0.f;
        }
        if (grB < n_rows) {
            short8 s = *reinterpret_cast<const short8*>(h_in + (size_t)grB * D + l16 * 8);
            #pragma unroll
            for (int j = 0; j < 8; j++) accB[j] = bf16_to_f32(s[j]);
            eB = offsets[grB]; endB = offsets[grB + 1];
        } else {
            #pragma unroll
            for (int j = 0; j < 8; j++) accB[j] = 0.f;
        }

        // joint 4+4 rounds: 8 x 16B gathers in flight
        while (eA + 3 < endA && eB + 3 < endB) {
            int a0 = csr_src[eA], a1 = csr_src[eA + 1], a2 = csr_src[eA + 2], a3 = csr_src[eA + 3];
            int b0 = csr_src[eB], b1 = csr_src[eB + 1], b2 = csr_src[eB + 2], b3 = csr_src[eB + 3];
            short8 va0 = *reinterpret_cast<const short8*>(h_in + (size_t)a0 * D + l16 * 8);
            short8 va1 = *reinterpret_cast<const short8*>(h_in + (size_t)a1 * D + l16 * 8);
            short8 va2 = *reinterpret_cast<const short8*>(h_in + (size_t)a2 * D + l16 * 8);
            short8 va3 = *reinterpret_cast<const short8*>(h_in + (size_t)a3 * D + l16 * 8);
            short8 vb0 = *reinterpret_cast<const short8*>(h_in + (size_t)b0 * D + l16 * 8);
            short8 vb1 = *reinterpret_cast<const short8*>(h_in + (size_t)b1 * D + l16 * 8);
            short8 vb2 = *reinterpret_cast<const short8*>(h_in + (size_t)b2 * D + l16 * 8);
            short8 vb3 = *reinterpret_cast<const short8*>(h_in + (size_t)b3 * D + l16 * 8);
            #pragma unroll
            for (int j = 0; j < 8; j++) {
                accA[j] += (bf16_to_f32(va0[j]) + bf16_to_f32(va1[j]))
                         + (bf16_to_f32(va2[j]) + bf16_to_f32(va3[j]));
                accB[j] += (bf16_to_f32(vb0[j]) + bf16_to_f32(vb1[j]))
                         + (bf16_to_f32(vb2[j]) + bf16_to_f32(vb3[j]));
            }
            eA += 4; eB += 4;
        }
        for (; eA + 3 < endA; eA += 4) {
            int a0 = csr_src[eA], a1 = csr_src[eA + 1], a2 = csr_src[eA + 2], a3 = csr_src[eA + 3];
            short8 va0 = *reinterpret_cast<const short8*>(h_in + (size_t)a0 * D + l16 * 8);
            short8 va1 = *reinterpret_cast<const short8*>(h_in + (size_t)a1 * D + l16 * 8);
            short8 va2 = *reinterpret_cast<const short8*>(h_in + (size_t)a2 * D + l16 * 8);
            short8 va3 = *reinterpret_cast<const short8*>(h_in + (size_t)a3 * D + l16 * 8);
            #pragma unroll
            for (int j = 0; j < 8; j++)
                accA[j] += (bf16_to_f32(va0[j]) + bf16_to_f32(va1[j]))
                         + (bf16_to_f32(va2[j]) + bf16_to_f32(va3[j]));
        }
        for (; eB + 3 < endB; eB += 4) {
            int b0 = csr_src[eB], b1 = csr_src[eB + 1], b2 = csr_src[eB + 2], b3 = csr_src[eB + 3];
            short8 vb0 = *reinterpret_cast<const short8*>(h_in + (size_t)b0 * D + l16 * 8);
            short8 vb1 = *reinterpret_cast<const short8*>(h_in + (size_t)b1 * D + l16 * 8);
            short8 vb2 = *reinterpret_cast<const short8*>(h_in + (size_t)b2 * D + l16 * 8);
            short8 vb3 = *reinterpret_cast<const short8*>(h_in + (size_t)b3 * D + l16 * 8);
            #pragma unroll
            for (int j = 0; j < 8; j++)
                accB[j] += (bf16_to_f32(vb0[j]) + bf16_to_f32(vb1[j]))
                         + (bf16_to_f32(vb2[j]) + bf16_to_f32(vb3[j]));
        }
        while (eA < endA && eB < endB) {
            int a0 = csr_src[eA];
            int b0 = csr_src[eB];
            short8 va0 = *reinterpret_cast<const short8*>(h_in + (size_t)a0 * D + l16 * 8);
            short8 vb0 = *reinterpret_cast<const short8*>(h_in + (size_t)b0 * D + l16 * 8);
            #pragma unroll
            for (int j = 0; j < 8; j++) {
                accA[j] += bf16_to_f32(va0[j]);
                accB[j] += bf16_to_f32(vb0[j]);
            }
            eA++; eB++;
        }
        for (; eA < endA; eA++) {
            int a0 = csr_src[eA];
            short8 va0 = *reinterpret_cast<const short8*>(h_in + (size_t)a0 * D + l16 * 8);
            #pragma unroll
            for (int j = 0; j < 8; j++) accA[j] += bf16_to_f32(va0[j]);
        }
        for (; eB < endB; eB++) {
            int b0 = csr_src[eB];
            short8 vb0 = *reinterpret_cast<const short8*>(h_in + (size_t)b0 * D + l16 * 8);
            #pragma unroll
            for (int j = 0; j < 8; j++) accB[j] += bf16_to_f32(vb0[j]);
        }

        short8 oA, oB;
        #pragma unroll
        for (int j = 0; j < 8; j++) { oA[j] = (short)bf16_rne(accA[j]); oB[j] = (short)bf16_rne(accB[j]); }
        *reinterpret_cast<short8*>(&zsh[(rA * 16 + (l16 ^ (rA & 15))) * 8]) = oA;
        *reinterpret_cast<short8*>(&zsh[(rB * 16 + (l16 ^ (rB & 15))) * 8]) = oB;
    }
    __syncthreads();

    const int lane = tid & 63;
    const int wave = tid >> 6;
    const int wr   = wave >> 1;
    const int wc   = wave & 1;
    const int lm   = lane & 15;
    const int quad = lane >> 4;

    floatx4 acc1[4];
    #pragma unroll
    for (int b = 0; b < 4; b++) acc1[b] = floatx4{0.f, 0.f, 0.f, 0.f};
    {
        const int r = wr * 16 + lm;
        #pragma unroll
        for (int ks = 0; ks < 4; ks++) {
            const int c = ks * 4 + quad;
            short8 av = *reinterpret_cast<const short8*>(&zsh[(r * 16 + (c ^ (r & 15))) * 8]);
            #pragma unroll
            for (int cs = 0; cs < 4; cs++) {
                int nn = wc * 64 + cs * 16 + lm;
                short8 bv = *reinterpret_cast<const short8*>(&wsh[(nn * 16 + (c ^ (nn & 15))) * 8]);
                acc1[cs] = __builtin_amdgcn_mfma_f32_16x16x32_bf16(av, bv, acc1[cs], 0, 0, 0);
            }
        }
    }
    __syncthreads();   // all wa + z1 reads done; wsh and zsh may be overwritten

    // load wb over wa (L2-hot; hides under the bias/relu VALU work below)
    #pragma unroll
    for (int i = 0; i < 4; i++) {
        int g = i * 512 + tid;
        int n = g >> 4, c = g & 15;
        int off = (n * 16 + (c ^ (n & 15))) * 8;
        *reinterpret_cast<short8*>(&wsh[off]) =
            *reinterpret_cast<const short8*>(wtb + n * D + c * 8);
    }

    #pragma unroll
    for (int cs = 0; cs < 4; cs++) {
        int col = wc * 64 + cs * 16 + lm;
        float bva = ba[col];
        int cj = col >> 3, ci = col & 7;
        #pragma unroll
        for (int reg = 0; reg < 4; reg++) {
            int r = wr * 16 + quad * 4 + reg;
            float v = fmaxf(acc1[cs][reg] + bva, 0.f);
            zsh[(r * 16 + (cj ^ (r & 15))) * 8 + ci] = (short)bf16_rne(v);
        }
    }
    __syncthreads();

    floatx4 acc2[4];
    #pragma unroll
    for (int b = 0; b < 4; b++) acc2[b] = floatx4{0.f, 0.f, 0.f, 0.f};
    {
        const int r = wr * 16 + lm;
        #pragma unroll
        for (int ks = 0; ks < 4; ks++) {
            const int c = ks * 4 + quad;
            short8 av = *reinterpret_cast<const short8*>(&zsh[(r * 16 + (c ^ (r & 15))) * 8]);
            #pragma unroll
            for (int cs = 0; cs < 4; cs++) {
                int nn = wc * 64 + cs * 16 + lm;
                short8 bv = *reinterpret_cast<const short8*>(&wsh[(nn * 16 + (c ^ (nn & 15))) * 8]);
                acc2[cs] = __builtin_amdgcn_mfma_f32_16x16x32_bf16(av, bv, acc2[cs], 0, 0, 0);
            }
        }
    }

    float psum[4];   // per-thread, per-cs column partial (only used on last layer)
    #pragma unroll
    for (int cs = 0; cs < 4; cs++) {
        int col = wc * 64 + cs * 16 + lm;
        float bvb = bb[col];
        float s = 0.f;
        #pragma unroll
        for (int reg = 0; reg < 4; reg++) {
            int r = row0 + wr * 16 + quad * 4 + reg;
            if (r < n_rows) {
                float v = fmaxf(acc2[cs][reg] + bvb, 0.f);
                short hv = (short)bf16_rne(v);
                h_out[(size_t)r * D + col] = hv;
                s += bf16_to_f32(hv);   // pool the rounded stored value (R8 pool semantics)
            }
        }
        psum[cs] = s;
    }

    if (pooled_accum != nullptr) {
        __syncthreads();                 // all gemm2 zsh reads done; reuse zsh as f32 scratch
        float* part = (float*)zsh;       // [16][128] floats = 8KB
        #pragma unroll
        for (int cs = 0; cs < 4; cs++)
            part[(wr * 4 + quad) * 128 + wc * 64 + cs * 16 + lm] = psum[cs];
        __syncthreads();
        if (tid < 128) {
            float s = 0.f;
            #pragma unroll
            for (int g = 0; g < 16; g++) s += part[g * 128 + tid];
            atomicAdd(&pooled_accum[tid], s);
        }
    }
}

// ---------------- final linear (fp32 exact) ----------------
__global__ void final_kernel(const float* __restrict__ pooled, const float* __restrict__ Wlin,
                             const float* __restrict__ blin, float* __restrict__ out) {
    const int j = threadIdx.x;
    __shared__ float p[D];
    p[j] = pooled[j];
    __syncthreads();
    float s = blin[j];
    #pragma unroll 8
    for (int k = 0; k < D; k++) s += p[k] * Wlin[k * D + j];
    out[j] = s;
}

extern "C" void kernel_launch(void* const* d_in, const int* in_sizes, int n_in,
                              void* d_out, int out_size, void* d_ws, size_t ws_size,
                              hipStream_t stream) {
    const int*   x    = (const int*)d_in[0];
    const int*   ei   = (const int*)d_in[1];
    const float* emb  = (const float*)d_in[2];
    const float* Wa   = (const float*)d_in[3];
    const float* ba   = (const float*)d_in[4];
    const float* Wb   = (const float*)d_in[5];
    const float* bb   = (const float*)d_in[6];
    const float* Wlin = (const float*)d_in[7];
    const float* blin = (const float*)d_in[8];
    float* out = (float*)d_out;

    const int N = in_sizes[0];
    const int E = in_sizes[1] / 2;
    const int* esrc = ei;
    const int* edst = ei + E;

    // workspace: H0 | H1 (bf16) | pooled | deg | offsets | cursor | bsums | csr_src | wt
    short* H0 = (short*)d_ws;                       // N*D
    short* H1 = H0 + (size_t)N * D;                 // N*D
    float* pooled = (float*)(H1 + (size_t)N * D);   // 128
    int* deg     = (int*)(pooled + 128);            // N
    int* offsets = deg + N;                         // N+1
    int* cursor  = offsets + (N + 1);               // N
    int* bsums   = cursor + N;                      // 4096
    int* csr_src = bsums + 4096;                    // E
    uintptr_t wt_addr = ((uintptr_t)(csr_src + E) + 15) & ~(uintptr_t)15;
    short* wt = (short*)wt_addr;                    // [10][128][128] bf16

    const int scan_blocks = (N + 1 + SCAN_TILE - 1) / SCAN_TILE;

    prepA_kernel<<<1024, 256, 0, stream>>>(x, emb, Wa, Wb, H0, wt, deg, pooled, N);
    hist_kernel<<<(E + 255) / 256, 256, 0, stream>>>(edst, deg, E);
    scan_sums_kernel<<<scan_blocks, 256, 0, stream>>>(deg, bsums, N);
    scan_bsums_kernel<<<1, 256, 0, stream>>>(bsums, scan_blocks);
    scan_final_kernel<<<scan_blocks, 256, 0, stream>>>(deg, bsums, offsets, cursor, N);
    fill_kernel<<<(E + 255) / 256, 256, 0, stream>>>(esrc, edst, cursor, csr_src, E);

    const int layer_blocks = (N + 63) / 64;
    short* hin = H0; short* hout = H1;
    for (int l = 0; l < NLAYERS; l++) {
        float* pacc = (l == NLAYERS - 1) ? pooled : nullptr;
        layer_kernel<<<layer_blocks, 512, 0, stream>>>(
            offsets, csr_src, hin,
            wt + (size_t)(2 * l) * D * D, wt + (size_t)(2 * l + 1) * D * D,
            ba + (size_t)l * D, bb + (size_t)l * D, hout, pacc, N);
        short* tmp = hin; hin = hout; hout = tmp;
    }

    final_kernel<<<1, 128, 0, stream>>>(pooled, Wlin, blin, out);
}

// Round 3
// 421.251 us; speedup vs baseline: 1.1189x; 1.1189x over previous
//
#include <hip/hip_runtime.h>

#define D 128
#define NLAYERS 5

using short8  = __attribute__((ext_vector_type(8))) short;
using short4v = __attribute__((ext_vector_type(4))) short;
using floatx4 = __attribute__((ext_vector_type(4))) float;

__device__ __forceinline__ unsigned bf16_rne(float x) {
    unsigned u = __float_as_uint(x);
    return (u + 0x7fffu + ((u >> 16) & 1u)) >> 16;
}
__device__ __forceinline__ float bf16_to_f32(short s) {
    return __uint_as_float(((unsigned)(unsigned short)s) << 16);
}

// ---------------- prepA: W transpose/bf16 + H0 gather + FUSED edge histogram ----------------
// deg/pooled are zeroed by a hipMemsetAsync issued before this kernel.
__global__ void prepA_kernel(const int* __restrict__ x, const float* __restrict__ emb,
                             const float* __restrict__ Wa, const float* __restrict__ Wb,
                             const int* __restrict__ edst,
                             short* __restrict__ H0, short* __restrict__ wt,
                             int* __restrict__ deg,
                             int n_nodes, int n_edges) {
    const int gtid = blockIdx.x * 256 + threadIdx.x;
    const int gsz  = gridDim.x * 256;
    for (int g = gtid; g < 2 * NLAYERS * D * D; g += gsz) {
        int mat = g >> 14, idx = g & 16383;
        int n = idx >> 7, k = idx & 127;
        const float* W = (mat & 1) ? (Wb + (size_t)(mat >> 1) * D * D)
                                   : (Wa + (size_t)(mat >> 1) * D * D);
        wt[g] = (short)bf16_rne(W[k * D + n]);
    }
    for (int t = gtid; t < n_nodes * 32; t += gsz) {
        int node = t >> 5, lane = t & 31;
        int s = x[node];
        const float4 v = *reinterpret_cast<const float4*>(emb + (size_t)s * D + lane * 4);
        short4v o;
        o[0] = (short)bf16_rne(v.x); o[1] = (short)bf16_rne(v.y);
        o[2] = (short)bf16_rne(v.z); o[3] = (short)bf16_rne(v.w);
        *reinterpret_cast<short4v*>(H0 + (size_t)node * D + lane * 4) = o;
    }
    for (int e = gtid; e < n_edges; e += gsz) atomicAdd(&deg[edst[e]], 1);
}

#define SCAN_TILE 1024
__global__ void scan_sums_kernel(const int* __restrict__ deg, int* __restrict__ bsums, int n) {
    __shared__ int red[256];
    int base = blockIdx.x * SCAN_TILE + threadIdx.x * 4;
    int s = 0;
    #pragma unroll
    for (int j = 0; j < 4; j++) {
        int i = base + j;
        if (i < n) s += deg[i];
    }
    red[threadIdx.x] = s;
    __syncthreads();
    for (int off = 128; off > 0; off >>= 1) {
        if (threadIdx.x < off) red[threadIdx.x] += red[threadIdx.x + off];
        __syncthreads();
    }
    if (threadIdx.x == 0) bsums[blockIdx.x] = red[0];
}

__global__ void scan_bsums_kernel(int* __restrict__ bsums, int nblocks) {
    __shared__ int sdata[256];
    int carry = 0;
    for (int base = 0; base < nblocks; base += 256) {
        int i = base + threadIdx.x;
        int v = (i < nblocks) ? bsums[i] : 0;
        sdata[threadIdx.x] = v;
        __syncthreads();
        for (int off = 1; off < 256; off <<= 1) {
            int t = (threadIdx.x >= off) ? sdata[threadIdx.x - off] : 0;
            __syncthreads();
            sdata[threadIdx.x] += t;
            __syncthreads();
        }
        int incl = sdata[threadIdx.x];
        if (i < nblocks) bsums[i] = carry + incl - v;
        carry += sdata[255];
        __syncthreads();
    }
}

__global__ void scan_final_kernel(const int* __restrict__ deg, const int* __restrict__ bsums,
                                  int* __restrict__ offsets, int* __restrict__ cursor, int n) {
    __shared__ int sdata[256];
    int base = blockIdx.x * SCAN_TILE + threadIdx.x * 4;
    int v[4];
    int s = 0;
    #pragma unroll
    for (int j = 0; j < 4; j++) {
        int i = base + j;
        v[j] = (i < n) ? deg[i] : 0;
        s += v[j];
    }
    sdata[threadIdx.x] = s;
    __syncthreads();
    for (int off = 1; off < 256; off <<= 1) {
        int t = (threadIdx.x >= off) ? sdata[threadIdx.x - off] : 0;
        __syncthreads();
        sdata[threadIdx.x] += t;
        __syncthreads();
    }
    int excl = sdata[threadIdx.x] - s + bsums[blockIdx.x];
    #pragma unroll
    for (int j = 0; j < 4; j++) {
        int i = base + j;
        if (i <= n) offsets[i] = excl;
        if (i < n) cursor[i] = excl;
        excl += v[j];
    }
}

__global__ void fill_kernel(const int* __restrict__ esrc, const int* __restrict__ edst,
                            int* __restrict__ cursor, int* __restrict__ csr_src, int n_edges) {
    int e = blockIdx.x * 256 + threadIdx.x;
    if (e >= n_edges) return;
    int pos = atomicAdd(&cursor[edst[e]], 1);
    csr_src[pos] = esrc[e];
}

// ---------------- fused layer (R8-exact math) + optional fused pool on last layer ----------------
// block: 64 nodes, 512 threads (8 waves). Node-parallel aggregation, 8 lanes/node x 32B/lane,
// 4-way edge unroll. (R1 layout — proven lowest L2-miss bytes; time tracks bytes at ~1700 GB/s.)
// LDS: zsh 16KB + ONE shared weight buffer 32KB = 48KB -> 3 blocks/CU.
// wb overwrites wa between GEMM1 and GEMM2 (hides under bias/relu VALU work).
// On the LAST layer h_out == nullptr: the output feeds only the pooled sum (kept in-register),
// so the 25.6MB h_out write is skipped entirely.
// 16B chunks XOR-swizzled: chunk c of row r at (c ^ (r&15)).
__global__ __launch_bounds__(512, 6) void layer_kernel(
        const int* __restrict__ offsets, const int* __restrict__ csr_src,
        const short* __restrict__ h_in, const short* __restrict__ wta,
        const short* __restrict__ wtb, const float* __restrict__ ba,
        const float* __restrict__ bb, short* __restrict__ h_out,
        float* __restrict__ pooled_accum, int n_rows) {
    __shared__ __align__(16) short zsh[64 * 128];     // z tile, then t tile, then pool scratch
    __shared__ __align__(16) short wsh[128 * 128];    // wa for GEMM1, then wb for GEMM2

    const int tid  = threadIdx.x;
    const int row0 = blockIdx.x * 64;

    #pragma unroll
    for (int i = 0; i < 4; i++) {
        int g = i * 512 + tid;
        int n = g >> 4, c = g & 15;
        int off = (n * 16 + (c ^ (n & 15))) * 8;
        *reinterpret_cast<short8*>(&wsh[off]) =
            *reinterpret_cast<const short8*>(wta + n * D + c * 8);
    }

    {
        const int r  = tid >> 3;
        const int l8 = tid & 7;
        const int gr = row0 + r;
        float acc[16];
        if (gr < n_rows) {
            const size_t cb = (size_t)gr * D + l8 * 16;
            short8 s0 = *reinterpret_cast<const short8*>(h_in + cb);
            short8 s1 = *reinterpret_cast<const short8*>(h_in + cb + 8);
            #pragma unroll
            for (int j = 0; j < 8; j++) { acc[j] = bf16_to_f32(s0[j]); acc[8 + j] = bf16_to_f32(s1[j]); }
            int beg = offsets[gr];
            int end = offsets[gr + 1];
            int e = beg;
            for (; e + 3 < end; e += 4) {
                int sA = csr_src[e];
                int sB = csr_src[e + 1];
                int sC = csr_src[e + 2];
                int sD = csr_src[e + 3];
                const short* pA = h_in + (size_t)sA * D + l8 * 16;
                const short* pB = h_in + (size_t)sB * D + l8 * 16;
                const short* pC = h_in + (size_t)sC * D + l8 * 16;
                const short* pD = h_in + (size_t)sD * D + l8 * 16;
                short8 a0 = *reinterpret_cast<const short8*>(pA);
                short8 a1 = *reinterpret_cast<const short8*>(pA + 8);
                short8 b0 = *reinterpret_cast<const short8*>(pB);
                short8 b1 = *reinterpret_cast<const short8*>(pB + 8);
                short8 c0 = *reinterpret_cast<const short8*>(pC);
                short8 c1 = *reinterpret_cast<const short8*>(pC + 8);
                short8 d0 = *reinterpret_cast<const short8*>(pD);
                short8 d1 = *reinterpret_cast<const short8*>(pD + 8);
                #pragma unroll
                for (int j = 0; j < 8; j++) {
                    acc[j]     += (bf16_to_f32(a0[j]) + bf16_to_f32(b0[j]))
                                + (bf16_to_f32(c0[j]) + bf16_to_f32(d0[j]));
                    acc[8 + j] += (bf16_to_f32(a1[j]) + bf16_to_f32(b1[j]))
                                + (bf16_to_f32(c1[j]) + bf16_to_f32(d1[j]));
                }
            }
            for (; e < end; e++) {
                int sA = csr_src[e];
                const short* pA = h_in + (size_t)sA * D + l8 * 16;
                short8 a0 = *reinterpret_cast<const short8*>(pA);
                short8 a1 = *reinterpret_cast<const short8*>(pA + 8);
                #pragma unroll
                for (int j = 0; j < 8; j++) {
                    acc[j]     += bf16_to_f32(a0[j]);
                    acc[8 + j] += bf16_to_f32(a1[j]);
                }
            }
        } else {
            #pragma unroll
            for (int j = 0; j < 16; j++) acc[j] = 0.f;
        }
        short8 o0, o1;
        #pragma unroll
        for (int j = 0; j < 8; j++) { o0[j] = (short)bf16_rne(acc[j]); o1[j] = (short)bf16_rne(acc[8 + j]); }
        const int c0i = 2 * l8, c1i = 2 * l8 + 1;
        *reinterpret_cast<short8*>(&zsh[(r * 16 + (c0i ^ (r & 15))) * 8]) = o0;
        *reinterpret_cast<short8*>(&zsh[(r * 16 + (c1i ^ (r & 15))) * 8]) = o1;
    }
    __syncthreads();

    const int lane = tid & 63;
    const int wave = tid >> 6;
    const int wr   = wave >> 1;
    const int wc   = wave & 1;
    const int lm   = lane & 15;
    const int quad = lane >> 4;

    floatx4 acc1[4];
    #pragma unroll
    for (int b = 0; b < 4; b++) acc1[b] = floatx4{0.f, 0.f, 0.f, 0.f};
    {
        const int r = wr * 16 + lm;
        #pragma unroll
        for (int ks = 0; ks < 4; ks++) {
            const int c = ks * 4 + quad;
            short8 av = *reinterpret_cast<const short8*>(&zsh[(r * 16 + (c ^ (r & 15))) * 8]);
            #pragma unroll
            for (int cs = 0; cs < 4; cs++) {
                int nn = wc * 64 + cs * 16 + lm;
                short8 bv = *reinterpret_cast<const short8*>(&wsh[(nn * 16 + (c ^ (nn & 15))) * 8]);
                acc1[cs] = __builtin_amdgcn_mfma_f32_16x16x32_bf16(av, bv, acc1[cs], 0, 0, 0);
            }
        }
    }
    __syncthreads();   // all wa + z1 reads done; wsh and zsh may be overwritten

    // load wb over wa (L2-hot; hides under the bias/relu VALU work below)
    #pragma unroll
    for (int i = 0; i < 4; i++) {
        int g = i * 512 + tid;
        int n = g >> 4, c = g & 15;
        int off = (n * 16 + (c ^ (n & 15))) * 8;
        *reinterpret_cast<short8*>(&wsh[off]) =
            *reinterpret_cast<const short8*>(wtb + n * D + c * 8);
    }

    #pragma unroll
    for (int cs = 0; cs < 4; cs++) {
        int col = wc * 64 + cs * 16 + lm;
        float bva = ba[col];
        int cj = col >> 3, ci = col & 7;
        #pragma unroll
        for (int reg = 0; reg < 4; reg++) {
            int r = wr * 16 + quad * 4 + reg;
            float v = fmaxf(acc1[cs][reg] + bva, 0.f);
            zsh[(r * 16 + (cj ^ (r & 15))) * 8 + ci] = (short)bf16_rne(v);
        }
    }
    __syncthreads();

    floatx4 acc2[4];
    #pragma unroll
    for (int b = 0; b < 4; b++) acc2[b] = floatx4{0.f, 0.f, 0.f, 0.f};
    {
        const int r = wr * 16 + lm;
        #pragma unroll
        for (int ks = 0; ks < 4; ks++) {
            const int c = ks * 4 + quad;
            short8 av = *reinterpret_cast<const short8*>(&zsh[(r * 16 + (c ^ (r & 15))) * 8]);
            #pragma unroll
            for (int cs = 0; cs < 4; cs++) {
                int nn = wc * 64 + cs * 16 + lm;
                short8 bv = *reinterpret_cast<const short8*>(&wsh[(nn * 16 + (c ^ (nn & 15))) * 8]);
                acc2[cs] = __builtin_amdgcn_mfma_f32_16x16x32_bf16(av, bv, acc2[cs], 0, 0, 0);
            }
        }
    }

    float psum[4];   // per-thread, per-cs column partial (only used on last layer)
    #pragma unroll
    for (int cs = 0; cs < 4; cs++) {
        int col = wc * 64 + cs * 16 + lm;
        float bvb = bb[col];
        float s = 0.f;
        #pragma unroll
        for (int reg = 0; reg < 4; reg++) {
            int r = row0 + wr * 16 + quad * 4 + reg;
            if (r < n_rows) {
                float v = fmaxf(acc2[cs][reg] + bvb, 0.f);
                short hv = (short)bf16_rne(v);      // round exactly as if stored (R8 pool semantics)
                if (h_out != nullptr) h_out[(size_t)r * D + col] = hv;
                s += bf16_to_f32(hv);
            }
        }
        psum[cs] = s;
    }

    if (pooled_accum != nullptr) {
        __syncthreads();                 // all gemm2 zsh reads done; reuse zsh as f32 scratch
        float* part = (float*)zsh;       // [16][128] floats = 8KB
        #pragma unroll
        for (int cs = 0; cs < 4; cs++)
            part[(wr * 4 + quad) * 128 + wc * 64 + cs * 16 + lm] = psum[cs];
        __syncthreads();
        if (tid < 128) {
            float s = 0.f;
            #pragma unroll
            for (int g = 0; g < 16; g++) s += part[g * 128 + tid];
            atomicAdd(&pooled_accum[tid], s);
        }
    }
}

// ---------------- final linear (fp32 exact) ----------------
__global__ void final_kernel(const float* __restrict__ pooled, const float* __restrict__ Wlin,
                             const float* __restrict__ blin, float* __restrict__ out) {
    const int j = threadIdx.x;
    __shared__ float p[D];
    p[j] = pooled[j];
    __syncthreads();
    float s = blin[j];
    #pragma unroll 8
    for (int k = 0; k < D; k++) s += p[k] * Wlin[k * D + j];
    out[j] = s;
}

extern "C" void kernel_launch(void* const* d_in, const int* in_sizes, int n_in,
                              void* d_out, int out_size, void* d_ws, size_t ws_size,
                              hipStream_t stream) {
    const int*   x    = (const int*)d_in[0];
    const int*   ei   = (const int*)d_in[1];
    const float* emb  = (const float*)d_in[2];
    const float* Wa   = (const float*)d_in[3];
    const float* ba   = (const float*)d_in[4];
    const float* Wb   = (const float*)d_in[5];
    const float* bb   = (const float*)d_in[6];
    const float* Wlin = (const float*)d_in[7];
    const float* blin = (const float*)d_in[8];
    float* out = (float*)d_out;

    const int N = in_sizes[0];
    const int E = in_sizes[1] / 2;
    const int* esrc = ei;
    const int* edst = ei + E;

    // workspace: H0 | H1 (bf16) | pooled | deg | offsets | cursor | bsums | csr_src | wt
    short* H0 = (short*)d_ws;                       // N*D
    short* H1 = H0 + (size_t)N * D;                 // N*D
    float* pooled = (float*)(H1 + (size_t)N * D);   // 128
    int* deg     = (int*)(pooled + 128);            // N
    int* offsets = deg + N;                         // N+1
    int* cursor  = offsets + (N + 1);               // N
    int* bsums   = cursor + N;                      // 4096
    int* csr_src = bsums + 4096;                    // E
    uintptr_t wt_addr = ((uintptr_t)(csr_src + E) + 15) & ~(uintptr_t)15;
    short* wt = (short*)wt_addr;                    // [10][128][128] bf16

    const int scan_blocks = (N + 1 + SCAN_TILE - 1) / SCAN_TILE;

    // zero pooled[128] + deg[N] in one contiguous memset (graph-capture-safe)
    hipMemsetAsync(pooled, 0, (size_t)(128 + N) * sizeof(int), stream);

    prepA_kernel<<<1024, 256, 0, stream>>>(x, emb, Wa, Wb, edst, H0, wt, deg, N, E);
    scan_sums_kernel<<<scan_blocks, 256, 0, stream>>>(deg, bsums, N);
    scan_bsums_kernel<<<1, 256, 0, stream>>>(bsums, scan_blocks);
    scan_final_kernel<<<scan_blocks, 256, 0, stream>>>(deg, bsums, offsets, cursor, N);
    fill_kernel<<<(E + 255) / 256, 256, 0, stream>>>(esrc, edst, cursor, csr_src, E);

    const int layer_blocks = (N + 63) / 64;
    short* hin = H0; short* hout = H1;
    for (int l = 0; l < NLAYERS; l++) {
        const bool last = (l == NLAYERS - 1);
        float* pacc = last ? pooled : nullptr;
        short* hdst = last ? nullptr : hout;   // last layer: output only feeds the pool
        layer_kernel<<<layer_blocks, 512, 0, stream>>>(
            offsets, csr_src, hin,
            wt + (size_t)(2 * l) * D * D, wt + (size_t)(2 * l + 1) * D * D,
            ba + (size_t)l * D, bb + (size_t)l * D, hdst, pacc, N);
        short* tmp = hin; hin = hout; hout = tmp;
    }

    final_kernel<<<1, 128, 0, stream>>>(pooled, Wlin, blin, out);
}